// Round 16
// baseline (513.262 us; speedup 1.0000x reference)
//
#include <hip/hip_runtime.h>
#include <hip/hip_bf16.h>
#include <stdint.h>

#define NB 16
#define NPT 2048
#define NS 512
#define NK 32
#define PTOT (NB*NS*NK)   // 262144 positions
#define EPSV 1e-5f

typedef __attribute__((ext_vector_type(8))) short short8;
typedef __attribute__((ext_vector_type(4))) float floatx4;

// ws layout (float indices)
#define WS_NEWXYZ 0            // 24576
// ST: L1 16 reps x (64 sum | 64 sq) @0..2048 | L2 @2048..4096 | L3 sum 8x128@4096 sq@5120 -> 6144
#define WS_ST     24576        // -> 30720
#define WS_W1BF   30720        // 4096 bf16 -> 32768
#define WS_W2BF   32768        // 8192 bf16 -> 36864
#define WS_W0R    36864        // 64x96 bf16 = 3072 fl -> 39936
#define WS_RAWMAX 39936        // 1048576 bf16 -> 564224
#define WS_PTS_TB 564224       // B*N*64 bf16 -> 1612800
#define WS_Y1     1612800      // 8388608 fl -> 10001408
#define WS_Y2     10001408     // -> 18390016  (~74MB)

__device__ __forceinline__ float bf2f(ushort u){ return __uint_as_float((uint32_t)u<<16); }
__device__ __forceinline__ ushort f2bf(float f){
  uint32_t u = __float_as_uint(f);
  return (ushort)((u + 0x7FFFu + ((u>>16)&1u)) >> 16);
}

template<int CTRL>
__device__ __forceinline__ double dppmax64f(double k){
  long long b = __double_as_longlong(k);
  int lo = (int)(uint32_t)b, hi = (int)(b>>32);
  int olo = __builtin_amdgcn_update_dpp(lo, lo, CTRL, 0xF, 0xF, false);
  int ohi = __builtin_amdgcn_update_dpp(hi, hi, CTRL, 0xF, 0xF, false);
  double o = __hiloint2double(ohi, olo);
  return fmax(o, k);
}

template<int CTRL>
__device__ __forceinline__ float dppaddf(float v){
  int o = __builtin_amdgcn_update_dpp(__float_as_int(v), __float_as_int(v), CTRL, 0xF, 0xF, false);
  return v + __int_as_float(o);
}
// sum within each row16 (valid in all lanes of the row)
__device__ __forceinline__ float rowsum16(float v){
  v = dppaddf<0xB1>(v);
  v = dppaddf<0x4E>(v);
  v = dppaddf<0x124>(v);
  v = dppaddf<0x128>(v);
  return v;
}

// ---------------- prep: fps single-wave (0-15) + transpose->bf16 (16-527) + wprep (528) ----------------
__global__ __launch_bounds__(256) void prep_kernel(const float* __restrict__ xyz,
    float* __restrict__ nxyz, float* __restrict__ out0,
    const float* __restrict__ pts, ushort* __restrict__ pts_tb,
    const float* __restrict__ w0, const float* __restrict__ w1, const float* __restrict__ w2,
    ushort* __restrict__ w0r, ushort* __restrict__ w1b, ushort* __restrict__ w2b,
    float* __restrict__ st)
{
  __shared__ union {
    struct { float4 lc[NPT]; int sel[NS]; } f;
    float tile[64][65];
  } sm;
  const int blk = blockIdx.x;
  const int tid = threadIdx.x;
  if (blk < 16){
    // ---- FPS: single wave, 32 pts/lane, no barriers in the loop ----
    const int b = blk;
    const int lane = tid & 63, wid = tid >> 6;
    const float* xb = xyz + (size_t)b*3*NPT;
    // all 256 threads fill the lc table (for lc[n] broadcast reads + epilogue)
    #pragma unroll
    for (int j=0;j<8;j++){
      int n = j*256 + tid;
      sm.f.lc[n] = make_float4(xb[n], xb[NPT+n], xb[2*NPT+n], 0.f);
    }
    if (tid==0) sm.f.sel[0]=0;
    __syncthreads();
    if (wid==0){
      float px[32], py[32], pz[32], dist[32];
      uint32_t lo_[32];
      #pragma unroll
      for (int j=0;j<32;j++){
        int n = j*64 + lane;
        px[j]=xb[n]; py[j]=xb[NPT+n]; pz[j]=xb[2*NPT+n];
        dist[j]=1e10f;
        lo_[j] = ~(uint32_t)n;
      }
      float4 c0 = sm.f.lc[0];
      float cx = c0.x, cy = c0.y, cz = c0.z;
      for (int t=1;t<NS;t++){
        double b0a = -1.0, b1a = -1.0, b2a = -1.0, b3a = -1.0;  // keys are >= 0
        #pragma unroll
        for (int j=0;j<32;j+=4){
          #pragma unroll
          for (int u=0;u<4;u++){
            float dx = __fsub_rn(px[j+u], cx);
            float dy = __fsub_rn(py[j+u], cy);
            float dz = __fsub_rn(pz[j+u], cz);
            float d  = __fadd_rn(__fadd_rn(__fmul_rn(dx,dx),__fmul_rn(dy,dy)),__fmul_rn(dz,dz));
            float dd = fminf(dist[j+u], d);
            dist[j+u] = dd;
            double k = __hiloint2double((int)__float_as_uint(dd), (int)lo_[j+u]);
            if (u==0) b0a = fmax(b0a, k);
            else if (u==1) b1a = fmax(b1a, k);
            else if (u==2) b2a = fmax(b2a, k);
            else b3a = fmax(b3a, k);
          }
        }
        double best = fmax(fmax(b0a,b1a), fmax(b2a,b3a));
        best = dppmax64f<0xB1>(best);    // quad xor1
        best = dppmax64f<0x4E>(best);    // quad xor2
        best = dppmax64f<0x124>(best);   // row_ror:4
        best = dppmax64f<0x128>(best);   // row_ror:8
        best = dppmax64f<0x142>(best);   // row_bcast15
        best = dppmax64f<0x143>(best);   // row_bcast31 -> lane63 = wave max
        long long bb = __double_as_longlong(best);
        uint32_t lo63 = (uint32_t)__builtin_amdgcn_readlane((int)(uint32_t)bb, 63);
        int n = (int)(~lo63);
        float4 cc = sm.f.lc[n];
        cx = cc.x; cy = cc.y; cz = cc.z;
        if (lane==0) sm.f.sel[t]=n;
      }
    }
    __syncthreads();
    for (int s = tid; s < NS; s += 256){
      int n = sm.f.sel[s];
      float4 cc = sm.f.lc[n];
      float* np_ = nxyz + ((size_t)b*NS + s)*3;
      np_[0]=cc.x; np_[1]=cc.y; np_[2]=cc.z;
      float* ob = out0 + (size_t)b*3*NS + s;
      ob[0]=cc.x; ob[NS]=cc.y; ob[2*NS]=cc.z;
    }
  } else if (blk < 528){
    const int t2 = blk - 16;
    const int b = t2 >> 5;
    const int n0 = (t2 & 31) * 64;
    const int lane = tid & 63;
    const int row4 = tid >> 6;
    const float* src = pts + (size_t)b*64*NPT;
    #pragma unroll
    for (int r=0; r<16; r++){
      int cc = r*4 + row4;
      sm.tile[cc][lane] = src[(size_t)cc*NPT + n0 + lane];
    }
    __syncthreads();
    ushort* dst = pts_tb + ((size_t)b*NPT + n0)*64;
    #pragma unroll
    for (int r=0; r<16; r++){
      int nn = r*4 + row4;
      dst[(size_t)nn*64 + lane] = f2bf(sm.tile[lane][nn]);
    }
  } else {
    for (int i = tid; i < 4096; i += 256) w1b[i] = f2bf(w1[i]);
    for (int i = tid; i < 8192; i += 256) w2b[i] = f2bf(w2[i]);
    for (int i = tid; i < 6144; i += 256) st[i] = 0.f;
    // w0 reorder: col 0-63 = pts weights (w0 col 3..66), 64-66 = xyz weights, 67-95 = 0
    for (int i = tid; i < 6144; i += 256){
      int o = i / 96, k = i - o*96;
      float v = (k < 64) ? w0[o*67 + 3 + k] : ((k < 67) ? w0[o*67 + (k-64)] : 0.f);
      w0r[i] = f2bf(v);
    }
  }
}

// ---------------- conv1 MFMA: two-phase ballq + 96->64 + fused L1 stats ----------------
__global__ __launch_bounds__(256) void conv1_mfma(const float* __restrict__ xyz,
    const ushort* __restrict__ pts_tb, const float* __restrict__ nxyz,
    const ushort* __restrict__ w0r, const float* __restrict__ b0,
    ushort* __restrict__ y1, float* __restrict__ st)
{
  __shared__ int gq[4][NK];
  __shared__ float lsum[4][64], lsq[4][64];
  const int tid = threadIdx.x;
  const int wid = tid>>6, lane = tid&63;
  const int q = lane>>4, nn = lane&15;
  const int g = blockIdx.x*4 + wid;          // group 0..8191
  const int b = g >> 9;
  const float* xb = xyz + (size_t)b*3*NPT;
  const float* cgp = nxyz + (size_t)g*3;
  const float cx = cgp[0], cy = cgp[1], cz = cgp[2];
  {
    const float r2 = 0.2f*0.2f;
    uint32_t mymask = 0;
    #pragma unroll
    for (int ch=0; ch<NPT/64; ch++){
      int n = ch*64 + lane;
      float dx = __fsub_rn(cx, xb[n]);
      float dy = __fsub_rn(cy, xb[NPT+n]);
      float dz = __fsub_rn(cz, xb[2*NPT+n]);
      float d  = __fadd_rn(__fadd_rn(__fmul_rn(dx,dx),__fmul_rn(dy,dy)),__fmul_rn(dz,dz));
      if (d <= r2) mymask |= (1u<<ch);
    }
    int cnt = 0, first = 0;
    for (int ch=0; ch<NPT/64 && cnt<NK; ch++){
      bool in = (mymask>>ch) & 1u;
      unsigned long long mask = __ballot(in);
      if (mask){
        if (cnt==0) first = ch*64 + (__ffsll((unsigned long long)mask)-1);
        if (in){
          int pos = cnt + __popcll(mask & ((1ull<<lane)-1ull));
          if (pos < NK) gq[wid][pos] = ch*64 + lane;
        }
        cnt += __popcll(mask);
      }
    }
    if (cnt < NK && lane >= cnt && lane < NK) gq[wid][lane] = first;
  }
  int n0 = gq[wid][nn], n1 = gq[wid][16+nn];
  float dx0 = xb[n0]-cx, dy0 = xb[NPT+n0]-cy, dz0 = xb[2*NPT+n0]-cz;
  float dx1 = xb[n1]-cx, dy1 = xb[NPT+n1]-cy, dz1 = xb[2*NPT+n1]-cz;
  floatx4 z4 = {0.f,0.f,0.f,0.f};
  floatx4 acc[4][2];
  #pragma unroll
  for (int mt=0;mt<4;mt++){ acc[mt][0]=z4; acc[mt][1]=z4; }
  const ushort* pr0 = pts_tb + ((size_t)b*NPT + n0)*64;
  const ushort* pr1 = pts_tb + ((size_t)b*NPT + n1)*64;
  #pragma unroll
  for (int kh=0; kh<2; kh++){
    short8 B0 = *(const short8*)(pr0 + kh*32 + q*8);
    short8 B1 = *(const short8*)(pr1 + kh*32 + q*8);
    #pragma unroll
    for (int mt=0; mt<4; mt++){
      short8 A = *(const short8*)(w0r + (mt*16+nn)*96 + kh*32 + q*8);
      acc[mt][0] = __builtin_amdgcn_mfma_f32_16x16x32_bf16(A, B0, acc[mt][0], 0,0,0);
      acc[mt][1] = __builtin_amdgcn_mfma_f32_16x16x32_bf16(A, B1, acc[mt][1], 0,0,0);
    }
  }
  {
    short8 B0 = {0,0,0,0,0,0,0,0}, B1 = {0,0,0,0,0,0,0,0};
    if (q==0){
      B0[0]=(short)f2bf(dx0); B0[1]=(short)f2bf(dy0); B0[2]=(short)f2bf(dz0);
      B1[0]=(short)f2bf(dx1); B1[1]=(short)f2bf(dy1); B1[2]=(short)f2bf(dz1);
    }
    #pragma unroll
    for (int mt=0; mt<4; mt++){
      short8 A = *(const short8*)(w0r + (mt*16+nn)*96 + 64 + q*8);
      acc[mt][0] = __builtin_amdgcn_mfma_f32_16x16x32_bf16(A, B0, acc[mt][0], 0,0,0);
      acc[mt][1] = __builtin_amdgcn_mfma_f32_16x16x32_bf16(A, B1, acc[mt][1], 0,0,0);
    }
  }
  float ss[4][4], sq2[4][4];
  #pragma unroll
  for (int mt=0;mt<4;mt++)
    #pragma unroll
    for (int r=0;r<4;r++){ ss[mt][r]=0.f; sq2[mt][r]=0.f; }
  #pragma unroll
  for (int nt=0; nt<2; nt++){
    int p = g*32 + nt*16 + nn;
    #pragma unroll
    for (int mt=0; mt<4; mt++){
      float v0 = acc[mt][nt][0] + b0[mt*16 + q*4 + 0];
      float v1 = acc[mt][nt][1] + b0[mt*16 + q*4 + 1];
      float v2 = acc[mt][nt][2] + b0[mt*16 + q*4 + 2];
      float v3 = acc[mt][nt][3] + b0[mt*16 + q*4 + 3];
      ss[mt][0]+=v0; ss[mt][1]+=v1; ss[mt][2]+=v2; ss[mt][3]+=v3;
      sq2[mt][0]=fmaf(v0,v0,sq2[mt][0]); sq2[mt][1]=fmaf(v1,v1,sq2[mt][1]);
      sq2[mt][2]=fmaf(v2,v2,sq2[mt][2]); sq2[mt][3]=fmaf(v3,v3,sq2[mt][3]);
      uint2 wv;
      wv.x = (uint32_t)f2bf(v0) | ((uint32_t)f2bf(v1)<<16);
      wv.y = (uint32_t)f2bf(v2) | ((uint32_t)f2bf(v3)<<16);
      *(uint2*)(y1 + (size_t)p*64 + mt*16 + q*4) = wv;
    }
  }
  #pragma unroll
  for (int mt=0;mt<4;mt++)
    #pragma unroll
    for (int r=0;r<4;r++){
      float sv = rowsum16(ss[mt][r]);
      float qv = rowsum16(sq2[mt][r]);
      if (nn==0){ lsum[wid][mt*16+q*4+r] = sv; lsq[wid][mt*16+q*4+r] = qv; }
    }
  __syncthreads();
  if (tid < 64){
    float s = lsum[0][tid]+lsum[1][tid]+lsum[2][tid]+lsum[3][tid];
    float q2v = lsq[0][tid]+lsq[1][tid]+lsq[2][tid]+lsq[3][tid];
    int rep = blockIdx.x & 15;
    atomicAdd(&st[rep*128 + tid], s);
    atomicAdd(&st[rep*128 + 64 + tid], q2v);
  }
}

// ---------------- conv2 MFMA: 64->64, affine prologue + fused L2 stats ----------------
__global__ __launch_bounds__(256) void conv2_mfma(const ushort* __restrict__ yin,
    float* __restrict__ st, const float* __restrict__ g0, const float* __restrict__ bt0,
    const ushort* __restrict__ Wb, const float* __restrict__ bias,
    ushort* __restrict__ yout)
{
  __shared__ float aAl[64], aBl[64];
  __shared__ float lsum[4][64], lsq[4][64];
  const int tid = threadIdx.x;
  if (tid < 64){
    float s=0.f, qv=0.f;
    #pragma unroll
    for (int r=0;r<16;r++){ s += st[r*128 + tid]; qv += st[r*128 + 64 + tid]; }
    float mean = s * (1.f/PTOT);
    float var  = qv * (1.f/PTOT) - mean*mean;
    float a = g0[tid] * rsqrtf(var + EPSV);
    aAl[tid] = a;
    aBl[tid] = fmaf(-mean, a, bt0[tid]);
  }
  __syncthreads();
  const int wid = tid>>6, lane = tid&63;
  const int q = lane>>4, nn = lane&15;
  const int p0 = (blockIdx.x*4 + wid) * 32;
  float a_[2][8], b_[2][8];
  #pragma unroll
  for (int kh=0;kh<2;kh++)
    #pragma unroll
    for (int j=0;j<8;j++){
      a_[kh][j] = aAl[kh*32 + q*8 + j];
      b_[kh][j] = aBl[kh*32 + q*8 + j];
    }
  short8 Af[4][2];
  #pragma unroll
  for (int mt=0;mt<4;mt++)
    #pragma unroll
    for (int kh=0;kh<2;kh++)
      Af[mt][kh] = *(const short8*)(Wb + (mt*16 + nn)*64 + kh*32 + q*8);
  float bias_[4][4];
  #pragma unroll
  for (int mt=0;mt<4;mt++)
    #pragma unroll
    for (int r=0;r<4;r++) bias_[mt][r] = bias[mt*16 + q*4 + r];
  floatx4 z = {0.f,0.f,0.f,0.f};
  floatx4 acc[4][2];
  #pragma unroll
  for (int mt=0;mt<4;mt++){ acc[mt][0]=z; acc[mt][1]=z; }
  #pragma unroll
  for (int nt=0;nt<2;nt++){
    #pragma unroll
    for (int kh=0;kh<2;kh++){
      short8 raw = *(const short8*)(yin + (size_t)(p0 + nt*16 + nn)*64 + kh*32 + q*8);
      short8 bf;
      #pragma unroll
      for (int j=0;j<8;j++){
        float f = bf2f((ushort)raw[j]);
        f = fmaxf(fmaf(f, a_[kh][j], b_[kh][j]), 0.f);
        bf[j] = (short)f2bf(f);
      }
      #pragma unroll
      for (int mt=0;mt<4;mt++)
        acc[mt][nt] = __builtin_amdgcn_mfma_f32_16x16x32_bf16(Af[mt][kh], bf, acc[mt][nt], 0,0,0);
    }
  }
  float ss[4][4], sq2[4][4];
  #pragma unroll
  for (int mt=0;mt<4;mt++)
    #pragma unroll
    for (int r=0;r<4;r++){ ss[mt][r]=0.f; sq2[mt][r]=0.f; }
  #pragma unroll
  for (int nt=0;nt<2;nt++){
    int p = p0 + nt*16 + nn;
    #pragma unroll
    for (int mt=0;mt<4;mt++){
      float v0 = acc[mt][nt][0] + bias_[mt][0];
      float v1 = acc[mt][nt][1] + bias_[mt][1];
      float v2 = acc[mt][nt][2] + bias_[mt][2];
      float v3 = acc[mt][nt][3] + bias_[mt][3];
      ss[mt][0]+=v0; ss[mt][1]+=v1; ss[mt][2]+=v2; ss[mt][3]+=v3;
      sq2[mt][0]=fmaf(v0,v0,sq2[mt][0]); sq2[mt][1]=fmaf(v1,v1,sq2[mt][1]);
      sq2[mt][2]=fmaf(v2,v2,sq2[mt][2]); sq2[mt][3]=fmaf(v3,v3,sq2[mt][3]);
      uint2 w;
      w.x = (uint32_t)f2bf(v0) | ((uint32_t)f2bf(v1)<<16);
      w.y = (uint32_t)f2bf(v2) | ((uint32_t)f2bf(v3)<<16);
      *(uint2*)(yout + (size_t)p*64 + mt*16 + q*4) = w;
    }
  }
  #pragma unroll
  for (int mt=0;mt<4;mt++)
    #pragma unroll
    for (int r=0;r<4;r++){
      float sv = rowsum16(ss[mt][r]);
      float qv = rowsum16(sq2[mt][r]);
      if (nn==0){ lsum[wid][mt*16+q*4+r] = sv; lsq[wid][mt*16+q*4+r] = qv; }
    }
  __syncthreads();
  if (tid < 64){
    float s = lsum[0][tid]+lsum[1][tid]+lsum[2][tid]+lsum[3][tid];
    float q2v = lsq[0][tid]+lsq[1][tid]+lsq[2][tid]+lsq[3][tid];
    int rep = blockIdx.x & 15;
    atomicAdd(&st[2048 + rep*128 + tid], s);
    atomicAdd(&st[2048 + rep*128 + 64 + tid], q2v);
  }
}

// ---------------- conv3 MFMA: 64->128, tile in LDS, fused group-max + L3 stats ----------------
__global__ __launch_bounds__(256) void conv3_mfma(const ushort* __restrict__ yin,
    float* __restrict__ st, const float* __restrict__ g1, const float* __restrict__ bt1,
    const ushort* __restrict__ Wb, const float* __restrict__ bias,
    ushort* __restrict__ rawmax)
{
  __shared__ ushort tile[64*132];   // 64 pos x 128 ch, pitch 132
  __shared__ float aAl[64], aBl[64];
  const int tid = threadIdx.x;
  if (tid < 64){
    float s=0.f, qv=0.f;
    #pragma unroll
    for (int r=0;r<16;r++){ s += st[2048 + r*128 + tid]; qv += st[2048 + r*128 + 64 + tid]; }
    float mean = s * (1.f/PTOT);
    float var  = qv * (1.f/PTOT) - mean*mean;
    float a = g1[tid] * rsqrtf(var + EPSV);
    aAl[tid] = a;
    aBl[tid] = fmaf(-mean, a, bt1[tid]);
  }
  __syncthreads();
  const int wid = tid>>6, lane = tid&63;
  const int q = lane>>4, nn = lane&15;
  const int p0 = (blockIdx.x*4 + wid) * 16;
  float a_[2][8], b_[2][8];
  #pragma unroll
  for (int kh=0;kh<2;kh++)
    #pragma unroll
    for (int j=0;j<8;j++){
      a_[kh][j] = aAl[kh*32 + q*8 + j];
      b_[kh][j] = aBl[kh*32 + q*8 + j];
    }
  short8 bfr[2];
  #pragma unroll
  for (int kh=0;kh<2;kh++){
    short8 raw = *(const short8*)(yin + (size_t)(p0 + nn)*64 + kh*32 + q*8);
    short8 bf;
    #pragma unroll
    for (int j=0;j<8;j++){
      float f = bf2f((ushort)raw[j]);
      f = fmaxf(fmaf(f, a_[kh][j], b_[kh][j]), 0.f);
      bf[j] = (short)f2bf(f);
    }
    bfr[kh] = bf;
  }
  #pragma unroll 1
  for (int mh=0;mh<2;mh++){
    floatx4 z = {0.f,0.f,0.f,0.f};
    floatx4 acc[4];
    short8 Af[4][2];
    #pragma unroll
    for (int mt=0;mt<4;mt++){
      acc[mt]=z;
      #pragma unroll
      for (int kh=0;kh<2;kh++)
        Af[mt][kh] = *(const short8*)(Wb + ((mh*4+mt)*16 + nn)*64 + kh*32 + q*8);
    }
    #pragma unroll
    for (int kh=0;kh<2;kh++)
      #pragma unroll
      for (int mt=0;mt<4;mt++)
        acc[mt] = __builtin_amdgcn_mfma_f32_16x16x32_bf16(Af[mt][kh], bfr[kh], acc[mt], 0,0,0);
    #pragma unroll
    for (int mt=0;mt<4;mt++){
      int m0 = (mh*4+mt)*16;
      float v0 = acc[mt][0] + bias[m0 + q*4 + 0];
      float v1 = acc[mt][1] + bias[m0 + q*4 + 1];
      float v2 = acc[mt][2] + bias[m0 + q*4 + 2];
      float v3 = acc[mt][3] + bias[m0 + q*4 + 3];
      uint2 w;
      w.x = (uint32_t)f2bf(v0) | ((uint32_t)f2bf(v1)<<16);
      w.y = (uint32_t)f2bf(v2) | ((uint32_t)f2bf(v3)<<16);
      *(uint2*)&tile[(wid*16 + nn)*132 + m0 + q*4] = w;
    }
  }
  __syncthreads();
  const int c = tid >> 1, half = tid & 1;
  float s = 0.f, q2 = 0.f, mx = -1e30f;
  #pragma unroll 4
  for (int it=0; it<32; it++){
    float f = bf2f(tile[(half*32 + it)*132 + c]);
    s += f; q2 = fmaf(f,f,q2); mx = fmaxf(mx, f);
  }
  rawmax[(size_t)(blockIdx.x*2 + half)*128 + c] = f2bf(mx);
  s  += __shfl_xor(s, 1, 64);
  q2 += __shfl_xor(q2, 1, 64);
  if (half==0){
    int rep = blockIdx.x & 7;
    atomicAdd(&st[4096 + rep*128 + c], s);
    atomicAdd(&st[5120 + rep*128 + c], q2);
  }
}

// ---------------- finalize: tiled transpose + affine+relu ----------------
__global__ __launch_bounds__(256) void finalize_kernel(const ushort* __restrict__ rawmax,
    const float* __restrict__ st, const float* __restrict__ g2, const float* __restrict__ bt2,
    float* __restrict__ out)
{
  __shared__ float tile[64][65];
  __shared__ float aAl[128], aBl[128];
  const int tid = threadIdx.x;
  if (tid < 128){
    float s=0.f, qv=0.f;
    #pragma unroll
    for (int r=0;r<8;r++){ s += st[4096 + r*128 + tid]; qv += st[5120 + r*128 + tid]; }
    float mean = s * (1.f/PTOT);
    float var  = qv * (1.f/PTOT) - mean*mean;
    float a = g2[tid] * rsqrtf(var + EPSV);
    aAl[tid] = a;
    aBl[tid] = fmaf(-mean, a, bt2[tid]);
  }
  __syncthreads();
  const int b  = blockIdx.x >> 4;
  const int ct = (blockIdx.x >> 3) & 1;
  const int stt = blockIdx.x & 7;
  const int c0 = ct*64, s0 = stt*64;
  const int lane = tid & 63, wid = tid >> 6;
  #pragma unroll
  for (int r=0;r<16;r++){
    int sl = r*4 + wid;
    tile[sl][lane] = bf2f(rawmax[((size_t)(b*512 + s0 + sl))*128 + c0 + lane]);
  }
  __syncthreads();
  #pragma unroll
  for (int r=0;r<16;r++){
    int cl = r*4 + wid;
    float a = aAl[c0+cl], bb = aBl[c0+cl];
    out[((size_t)(b*128 + c0 + cl))*512 + s0 + lane] = fmaxf(fmaf(tile[lane][cl], a, bb), 0.f);
  }
}

extern "C" void kernel_launch(void* const* d_in, const int* in_sizes, int n_in,
                              void* d_out, int out_size, void* d_ws, size_t ws_size,
                              hipStream_t stream) {
  const float* xyz = (const float*)d_in[0];
  const float* pts = (const float*)d_in[1];
  const float* w0  = (const float*)d_in[2];
  const float* b0  = (const float*)d_in[3];
  const float* g0  = (const float*)d_in[4];
  const float* bt0 = (const float*)d_in[5];
  const float* w1  = (const float*)d_in[6];
  const float* b1  = (const float*)d_in[7];
  const float* g1  = (const float*)d_in[8];
  const float* bt1 = (const float*)d_in[9];
  const float* w2  = (const float*)d_in[10];
  const float* b2  = (const float*)d_in[11];
  const float* g2  = (const float*)d_in[12];
  const float* bt2 = (const float*)d_in[13];
  float* out = (float*)d_out;
  float* ws  = (float*)d_ws;

  float* nxyz = ws + WS_NEWXYZ;
  float* st   = ws + WS_ST;
  ushort* w0r = (ushort*)(ws + WS_W0R);
  ushort* w1b = (ushort*)(ws + WS_W1BF);
  ushort* w2b = (ushort*)(ws + WS_W2BF);
  ushort* rawmax = (ushort*)(ws + WS_RAWMAX);
  ushort* pts_tb = (ushort*)(ws + WS_PTS_TB);
  ushort* y1 = (ushort*)(ws + WS_Y1);
  ushort* y2 = (ushort*)(ws + WS_Y2);

  prep_kernel<<<529,256,0,stream>>>(xyz, nxyz, out, pts, pts_tb, w0, w1, w2, w0r, w1b, w2b, st);
  conv1_mfma<<<2048,256,0,stream>>>(xyz, pts_tb, nxyz, w0r, b0, y1, st);
  conv2_mfma<<<2048,256,0,stream>>>(y1, st, g0, bt0, w1b, b1, y2);
  conv3_mfma<<<4096,256,0,stream>>>(y2, st, g1, bt1, w2b, b2, rawmax);
  finalize_kernel<<<256,256,0,stream>>>(rawmax, st, g2, bt2, out + NB*3*NS);
}